// Round 14
// baseline (447.179 us; speedup 1.0000x reference)
//
#include <hip/hip_runtime.h>

#define BATCH 16384
#define CH 512
#define EPSBN 1e-5f

typedef __attribute__((ext_vector_type(8))) short short8;
typedef __attribute__((ext_vector_type(4))) float f32x4;
typedef __attribute__((ext_vector_type(4))) unsigned short ushort4v;

#define GLOAD16(gp, lp) __builtin_amdgcn_global_load_lds( \
    (const __attribute__((address_space(1))) void*)(gp),  \
    (__attribute__((address_space(3))) void*)(lp), 16, 0, 0)

// edge table: etab[node-1][j] = edge id; bct[e] = B-weight counter
__constant__ int d_etab[6][6] = {
  {0,0,0,0,0,0},
  {1,6,0,0,0,0},
  {2,7,11,0,0,0},
  {3,8,12,15,0,0},
  {4,9,13,16,18,0},
  {5,10,14,17,19,20}};
__constant__ int d_bct[21] = {0,0,0,0,0,0, 0,1,3,6,10, 2,4,7,11, 5,8,12, 9,13, 14};

static __device__ __forceinline__ long woff(int e){
  return (e < 6) ? (long)e*524288 : 3145728L + (long)d_bct[e]*262144;
}

static __device__ __forceinline__ unsigned short f2b(float f){
  union { float f; unsigned u; } v; v.f = f;
  unsigned r = v.u + 0x7fffu + ((v.u >> 16) & 1u);
  return (unsigned short)(r >> 16);
}
static __device__ __forceinline__ float b2f(unsigned short u){
  union { unsigned u; float f; } v; v.u = ((unsigned)u) << 16; return v.f;
}
static __device__ __forceinline__ float actf(int act, float v){
  if (act == 0) return fmaxf(v, 0.f);
  if (act == 1) return 1.f/(1.f + __expf(-v));
  float e = __expf(2.f*v);                    // tanh = 1 - 2/(e^{2v}+1)
  return 1.f - 2.f/(e + 1.f);
}

// per-column (sum, sumsq) atomic accumulation; 4 lq-lanes share a column
static __device__ __forceinline__ void col_stats_atomic(
    float vs, float vq, int cn, int slot, float* partw){
  vs += __shfl_xor(vs, 16); vs += __shfl_xor(vs, 32);
  vq += __shfl_xor(vq, 16); vq += __shfl_xor(vq, 32);
  if (((threadIdx.x) & 63) < 16){
    atomicAdd(&partw[((long)slot*CH + cn)*2    ], vs);
    atomicAdd(&partw[((long)slot*CH + cn)*2 + 1], vq);
  }
}
// slots: 0..5 = partA[e] (gemmA outputs); 6+j = partS[state j]

static __device__ __forceinline__ void ms_from(const float* part, int slot, int cn,
                                               float& mu, float& var){
  long sl = ((long)slot*CH + cn)*2;
  float s = part[sl], q = part[sl+1];
  mu = s * (1.f/16384.f);
  var = fmaxf(q * (1.f/16384.f) - mu*mu, 0.f);
}
static __device__ __forceinline__ float alphaA(int id, float v){
  float s1r = rsqrtf(v + EPSBN);
  float vz = v / (v + EPSBN);
  return (id==0) ? (s1r * (1.f/9.f) * rsqrtf(vz*(1.f/81.f) + EPSBN))
                 : (s1r * rsqrtf(vz + EPSBN));
}
static __device__ __forceinline__ float alphaB(int id, float v){
  return (id==0) ? ((1.f/9.f) * rsqrtf(v*(1.f/81.f) + EPSBN))
                 : rsqrtf(v + EPSBN);
}

__global__ void k_sentinel(float* out){ out[0] = 1.0e6f; }

// ---------------- index / wscale ----------------
__global__ void k_index(const float* __restrict__ ap, const float* __restrict__ gum,
                        int* __restrict__ idx, float* __restrict__ wsc){
  int e = threadIdx.x;
  if (e >= 21) return;
  const float* a = ap + e*9;
  const float* g = gum + e*9;
  float m = a[0];
  for (int o=1;o<9;o++) m = fmaxf(m, a[o]);
  float s = 0.f;
  for (int o=0;o<9;o++) s += expf(a[o]-m);
  float lse = m + logf(s);
  float lg[9]; float lm = -1e30f;
  for (int o=0;o<9;o++){ lg[o] = (a[o]-lse+g[o]) / 10.0f; lm = fmaxf(lm, lg[o]); }
  float ss = 0.f;
  for (int o=0;o<9;o++) ss += expf(lg[o]-lm);
  int bi = 0; float bp = -1.f;
  for (int o=0;o<9;o++){
    float p = expf(lg[o]-lm)/ss;
    if (p > bp){ bp = p; bi = o; }
  }
  idx[e] = bi;
  wsc[e] = (1.0f - bp) + bp;
}

// ---------------- fp32 -> bf16 (vector4, grid-stride) ----------------
__global__ void k_f2b4(const float* __restrict__ in, unsigned short* __restrict__ outp, long n4){
  long stride = (long)gridDim.x*blockDim.x;
  for (long i = (long)blockIdx.x*blockDim.x + threadIdx.x; i < n4; i += stride){
    const float4 v = ((const float4*)in)[i];
    ushort4v o;
    o[0] = f2b(v.x); o[1] = f2b(v.y); o[2] = f2b(v.z); o[3] = f2b(v.w);
    ((ushort4v*)outp)[i] = o;
  }
}

// ---------------- all selected weights -> bf16 slots ----------------
__global__ void k_wconv_all(const int* __restrict__ idxp,
                            const float* __restrict__ dwA, const float* __restrict__ pwA,
                            const float* __restrict__ gwA, const float* __restrict__ dwB,
                            const float* __restrict__ gwB,
                            unsigned short* __restrict__ Wball){
  int e = blockIdx.x >> 7;          // 21 edges x 128 blocks
  int blk = blockIdx.x & 127;
  int id = idxp[e];
  const float* src; long n;
  if (e < 6){
    int a = e;
    if (id >= 2 && id <= 4){ n = 524288; src = dwA + ((long)a*3 + (id-2))*n; }
    else if (id < 2)       { n = 524288; src = pwA + ((long)a*2 + id)*n; }
    else if (id <= 7)      { n = 131072; src = gwA + ((long)a*3 + (id-5))*131072; }
    else return;
  } else {
    int b = d_bct[e];
    if (id >= 2 && id <= 4)     { n = 262144; src = dwB + ((long)b*3 + (id-2))*n; }
    else if (id >= 5 && id <= 7){ n = 65536;  src = gwB + ((long)b*3 + (id-5))*65536; }
    else return;
  }
  unsigned short* dst = Wball + woff(e);
  long n4 = n >> 2;
  long stride = 128*256;
  for (long i = (long)blk*256 + threadIdx.x; i < n4; i += stride){
    const float4 v = ((const float4*)src)[i];
    ushort4v o;
    o[0] = f2b(v.x); o[1] = f2b(v.y); o[2] = f2b(v.z); o[3] = f2b(v.w);
    ((ushort4v*)dst)[i] = o;
  }
}

// ---------------- batched A-edge GEMMs: 256x128 tile, BK=64, 4-phase interleave ----------------
// 8 waves (2M x 4N), per-wave 128x32 out, acc[8][2]; 3 LDS K-tile buffers (144 KB);
// counted vmcnt(6) at K-tile entry only; setprio around each 8-MFMA cluster.
__global__ __launch_bounds__(512, 2) void k_gemmA_all(
    const unsigned short* __restrict__ xb, const unsigned short* __restrict__ Wball,
    unsigned short* __restrict__ s0, unsigned short* __restrict__ s1,
    unsigned short* __restrict__ s2, unsigned short* __restrict__ s3,
    unsigned short* __restrict__ s4, unsigned short* __restrict__ pre6,
    const float* __restrict__ dbA, const float* __restrict__ gbA,
    const int* __restrict__ idxp, const float* __restrict__ wscp,
    float* __restrict__ partw)
{
  int e = blockIdx.x >> 8;          // 6 edges x 256 blocks
  int id = idxp[e];
  if (id == 8) return;
  unsigned short* target;
  switch(e){ case 0: target=s0; break; case 1: target=s1; break; case 2: target=s2; break;
             case 3: target=s3; break; case 4: target=s4; break; default: target=pre6; }
  bool pool = (id < 2);
  bool grp = (id >= 5);
  int K = grp ? 256 : 1024;
  int act = pool ? 0 : (grp ? id-5 : id-2);
  float we = wscp[e];

  int inner = blockIdx.x & 255;
  int lg = (inner & 7) * 32 + (inner >> 3);   // XCD swizzle, 256%8==0 bijective
  int rowTile = lg >> 2, colTile = lg & 3;
  int row0 = rowTile * 256, col0 = colTile * 128;

  int t = threadIdx.x;
  int lane = t & 63, wave = t >> 6;
  int wm = wave >> 2, wn = wave & 3;          // wm: 128-row half, wn: 32-col strip
  int l16 = lane & 15, lq = lane >> 4;

  __shared__ unsigned short LDS[73728];       // 3 x (A 16384 + B 8192) shorts = 144 KB

  // staging: thread t covers row (i*64 + t/8), 16B chunk (t&7), swizzled source
  int srow = t >> 3;
  int schunk = (t & 7) ^ (srow & 7);
  const unsigned short* gA = xb + (grp ? (long)colTile*K : 0)
                              + (long)(row0 + srow)*1024 + schunk*8;
  const unsigned short* gB = Wball + (long)e*524288 + (long)col0*K
                              + (long)srow*K + schunk*8;

  // read offsets (shorts, within buffer); physical chunk = logical ^ (row&7)
  int aoff[8][2], boff[2][2];
  #pragma unroll
  for (int mf=0; mf<8; mf++){
    int R = wm*128 + mf*16 + l16;
    #pragma unroll
    for (int kh=0; kh<2; kh++)
      aoff[mf][kh] = R*64 + (((kh<<2)|lq) ^ (R&7))*8;
  }
  #pragma unroll
  for (int nf=0; nf<2; nf++){
    int C = wn*32 + nf*16 + l16;
    #pragma unroll
    for (int kh=0; kh<2; kh++)
      boff[nf][kh] = 16384 + C*64 + (((kh<<2)|lq) ^ (C&7))*8;
  }

  f32x4 acc[8][2];
  #pragma unroll
  for (int mf=0; mf<8; mf++){ acc[mf][0]=(f32x4){0,0,0,0}; acc[mf][1]=(f32x4){0,0,0,0}; }

  auto STAGE_A = [&](int tt, int tb, int i){
    GLOAD16(gA + (long)tt*64 + (long)i*65536, &LDS[tb*24576 + i*4096 + t*8]);
  };
  auto STAGE_B = [&](int tt, int tb, int i){
    GLOAD16(gB + (long)tt*64 + (long)i*64*K, &LDS[tb*24576 + 16384 + i*4096 + t*8]);
  };

  int nk = K >> 6;
  // prologue: stage tiles 0,1 (6 loads each)
  #pragma unroll
  for (int i=0;i<4;i++) STAGE_A(0,0,i);
  #pragma unroll
  for (int i=0;i<2;i++) STAGE_B(0,0,i);
  #pragma unroll
  for (int i=0;i<4;i++) STAGE_A(1,1,i);
  #pragma unroll
  for (int i=0;i<2;i++) STAGE_B(1,1,i);

  int cb = 0;
  for (int kt = 0; kt < nk; ++kt){
    if (kt+1 < nk) { asm volatile("s_waitcnt vmcnt(6)" ::: "memory"); }
    else           { asm volatile("s_waitcnt vmcnt(0)" ::: "memory"); }
    __builtin_amdgcn_s_barrier();
    const unsigned short* buf = &LDS[cb*24576];
    int tt = kt + 2;
    int tb = (cb >= 1) ? cb-1 : cb+2;
    bool st = (tt < nk);

    short8 a[4], b[2];
    // ---- phase 0: kh=0, mh=0 ----
    b[0] = *(const short8*)(buf + boff[0][0]);
    b[1] = *(const short8*)(buf + boff[1][0]);
    a[0] = *(const short8*)(buf + aoff[0][0]);
    a[1] = *(const short8*)(buf + aoff[1][0]);
    a[2] = *(const short8*)(buf + aoff[2][0]);
    a[3] = *(const short8*)(buf + aoff[3][0]);
    if (pool){
      #pragma unroll
      for (int m=0;m<4;m++)
        #pragma unroll
        for (int q=0;q<8;q++) a[m][q] = (a[m][q] < (short)0) ? (short)0 : a[m][q];
    }
    if (st){ STAGE_A(tt,tb,0); STAGE_A(tt,tb,1); }
    __builtin_amdgcn_s_setprio(1);
    #pragma unroll
    for (int m=0;m<4;m++){
      acc[m][0] = __builtin_amdgcn_mfma_f32_16x16x32_bf16(a[m], b[0], acc[m][0], 0,0,0);
      acc[m][1] = __builtin_amdgcn_mfma_f32_16x16x32_bf16(a[m], b[1], acc[m][1], 0,0,0);
    }
    __builtin_amdgcn_s_setprio(0);
    __builtin_amdgcn_s_barrier();
    // ---- phase 1: kh=0, mh=1 ----
    a[0] = *(const short8*)(buf + aoff[4][0]);
    a[1] = *(const short8*)(buf + aoff[5][0]);
    a[2] = *(const short8*)(buf + aoff[6][0]);
    a[3] = *(const short8*)(buf + aoff[7][0]);
    if (pool){
      #pragma unroll
      for (int m=0;m<4;m++)
        #pragma unroll
        for (int q=0;q<8;q++) a[m][q] = (a[m][q] < (short)0) ? (short)0 : a[m][q];
    }
    if (st){ STAGE_A(tt,tb,2); STAGE_A(tt,tb,3); }
    __builtin_amdgcn_s_setprio(1);
    #pragma unroll
    for (int m=0;m<4;m++){
      acc[4+m][0] = __builtin_amdgcn_mfma_f32_16x16x32_bf16(a[m], b[0], acc[4+m][0], 0,0,0);
      acc[4+m][1] = __builtin_amdgcn_mfma_f32_16x16x32_bf16(a[m], b[1], acc[4+m][1], 0,0,0);
    }
    __builtin_amdgcn_s_setprio(0);
    __builtin_amdgcn_s_barrier();
    // ---- phase 2: kh=1, mh=0 ----
    b[0] = *(const short8*)(buf + boff[0][1]);
    b[1] = *(const short8*)(buf + boff[1][1]);
    a[0] = *(const short8*)(buf + aoff[0][1]);
    a[1] = *(const short8*)(buf + aoff[1][1]);
    a[2] = *(const short8*)(buf + aoff[2][1]);
    a[3] = *(const short8*)(buf + aoff[3][1]);
    if (pool){
      #pragma unroll
      for (int m=0;m<4;m++)
        #pragma unroll
        for (int q=0;q<8;q++) a[m][q] = (a[m][q] < (short)0) ? (short)0 : a[m][q];
    }
    if (st){ STAGE_B(tt,tb,0); }
    __builtin_amdgcn_s_setprio(1);
    #pragma unroll
    for (int m=0;m<4;m++){
      acc[m][0] = __builtin_amdgcn_mfma_f32_16x16x32_bf16(a[m], b[0], acc[m][0], 0,0,0);
      acc[m][1] = __builtin_amdgcn_mfma_f32_16x16x32_bf16(a[m], b[1], acc[m][1], 0,0,0);
    }
    __builtin_amdgcn_s_setprio(0);
    __builtin_amdgcn_s_barrier();
    // ---- phase 3: kh=1, mh=1 ----
    a[0] = *(const short8*)(buf + aoff[4][1]);
    a[1] = *(const short8*)(buf + aoff[5][1]);
    a[2] = *(const short8*)(buf + aoff[6][1]);
    a[3] = *(const short8*)(buf + aoff[7][1]);
    if (pool){
      #pragma unroll
      for (int m=0;m<4;m++)
        #pragma unroll
        for (int q=0;q<8;q++) a[m][q] = (a[m][q] < (short)0) ? (short)0 : a[m][q];
    }
    if (st){ STAGE_B(tt,tb,1); }
    __builtin_amdgcn_s_setprio(1);
    #pragma unroll
    for (int m=0;m<4;m++){
      acc[4+m][0] = __builtin_amdgcn_mfma_f32_16x16x32_bf16(a[m], b[0], acc[4+m][0], 0,0,0);
      acc[4+m][1] = __builtin_amdgcn_mfma_f32_16x16x32_bf16(a[m], b[1], acc[4+m][1], 0,0,0);
    }
    __builtin_amdgcn_s_setprio(0);
    // (loop-head vmcnt+barrier serves as the phase-3 trailing barrier)
    cb = (cb+1 == 3) ? 0 : cb+1;
  }

  // epilogue: activation/scale, bf16 store, inline column stats
  #pragma unroll
  for (int nf=0; nf<2; nf++){
    int cn = col0 + wn*32 + nf*16 + l16;
    float bv = pool ? 0.f : ((grp ? gbA : dbA) + ((long)e*3 + act)*CH)[cn];
    float cs = 0.f, cq = 0.f;
    #pragma unroll
    for (int mf=0; mf<8; mf++)
      #pragma unroll
      for (int r=0;r<4;r++){
        int row = row0 + wm*128 + mf*16 + lq*4 + r;
        long off = (long)row*CH + cn;
        float v = pool ? acc[mf][nf][r] : (we * actf(act, acc[mf][nf][r] + bv));
        target[off] = f2b(v);
        cs += v; cq += v*v;
      }
    col_stats_atomic(cs, cq, cn, e, partw);
  }
}

// ---------------- node-1 finalize: s1 transform (pool) / zero / stats only ----------------
__global__ __launch_bounds__(512, 4) void k_fix1(
    unsigned short* __restrict__ s1, const float* __restrict__ part,
    float* __restrict__ partw, const int* __restrict__ idxp,
    const float* __restrict__ wscp)
{
  int id = idxp[0];
  float we = wscp[0];

  int bid = blockIdx.x;
  int lg = (bid & 7) * 64 + (bid >> 3);
  int rowTile = lg >> 2, colTile = lg & 3;
  int row0 = rowTile * 128, col0 = colTile * 128;

  int t = threadIdx.x;
  int lane = t & 63, wave = t >> 6;
  int wm = wave >> 2, wn = wave & 3;
  int l16 = lane & 15, lq = lane >> 4;

  #pragma unroll
  for (int n=0;n<2;n++){
    int cn = col0 + wn*32 + n*16 + l16;
    float cs = 0.f, cq = 0.f;
    float mu = 0.f, al = 0.f;
    if (id < 2){
      float var; ms_from(part, 0, cn, mu, var);
      al = alphaA(id, var);
    }
    #pragma unroll
    for (int m=0;m<4;m++)
      #pragma unroll
      for (int r=0;r<4;r++){
        int row = row0 + wm*64 + m*16 + lq*4 + r;
        long off = (long)row*CH + cn;
        float v;
        if (id == 8){ v = 0.f; s1[off] = 0; }
        else if (id < 2){ v = we * (b2f(s1[off]) - mu) * al; s1[off] = f2b(v); }
        else { v = b2f(s1[off]); }
        cs += v; cq += v*v;
      }
    col_stats_atomic(cs, cq, cn, 6+1, partw);
  }
}

// ---------------- fused per-node kernel: merge preA + B-edge GEMMs + inline stats ----------------
__global__ __launch_bounds__(512, 4) void k_fused(
    int node,
    const unsigned short* __restrict__ pre,
    const unsigned short* __restrict__ sb0, const unsigned short* __restrict__ sb1,
    const unsigned short* __restrict__ sb2, const unsigned short* __restrict__ sb3,
    const unsigned short* __restrict__ sb4,
    unsigned short* __restrict__ sbout, float* __restrict__ outf,
    const unsigned short* __restrict__ Wball,
    const float* __restrict__ dbB, const float* __restrict__ gbB,
    const float* __restrict__ part, float* __restrict__ partw,
    const int* __restrict__ idxp, const float* __restrict__ wscp)
{
  int bid = blockIdx.x;
  int lg = (bid & 7) * 64 + (bid >> 3);      // 512 blocks, bijective
  int rowTile = lg >> 2, colTile = lg & 3;
  int row0 = rowTile * 128, col0 = colTile * 128;

  int t = threadIdx.x;
  int lane = t & 63, wave = t >> 6;
  int wm = wave >> 2, wn = wave & 3;
  int l16 = lane & 15, lq = lane >> 4;

  __shared__ unsigned short LDS[24576];   // A x3, B x3

  int ra = t >> 2;
  int ca = (((t & 3) ^ ((ra >> 1) & 3)) << 3);
  int aoff[4], boff[2];
  #pragma unroll
  for (int m=0;m<4;m++){ int R = wm*64 + m*16 + l16; aoff[m] = R*32 + ((lq ^ ((R>>1)&3))<<3); }
  #pragma unroll
  for (int n=0;n<2;n++){ int C = wn*32 + n*16 + l16; boff[n] = C*32 + ((lq ^ ((C>>1)&3))<<3); }

  f32x4 facc[4][2];
  #pragma unroll
  for (int m=0;m<4;m++){ facc[m][0]=(f32x4){0,0,0,0}; facc[m][1]=(f32x4){0,0,0,0}; }

  for (int jj = 0; jj < node; ++jj){
    int e = d_etab[node-1][jj];
    int id = idxp[e];
    if (id == 8) continue;
    float we = wscp[e];

    if (jj == 0){
      // merge precomputed A-edge term (pre aliases sbout; same per-thread offsets)
      if (id < 2){
        #pragma unroll
        for (int n=0;n<2;n++){
          int cn = col0 + wn*32 + n*16 + l16;
          float mu, var; ms_from(part, e, cn, mu, var);
          float al = alphaA(id, var);
          #pragma unroll
          for (int m=0;m<4;m++){
            int rowb = row0 + wm*64 + m*16 + lq*4;
            #pragma unroll
            for (int r=0;r<4;r++)
              facc[m][n][r] += we * (b2f(pre[(long)(rowb+r)*CH + cn]) - mu) * al;
          }
        }
      } else {
        #pragma unroll
        for (int n=0;n<2;n++){
          int cn = col0 + wn*32 + n*16 + l16;
          #pragma unroll
          for (int m=0;m<4;m++){
            int rowb = row0 + wm*64 + m*16 + lq*4;
            #pragma unroll
            for (int r=0;r<4;r++)
              facc[m][n][r] += b2f(pre[(long)(rowb+r)*CH + cn]);
          }
        }
      }
      continue;
    }

    const unsigned short* st;
    switch(jj){ case 1: st=sb0; break; case 2: st=sb1; break;
                case 3: st=sb2; break; case 4: st=sb3; break; default: st=sb4; }

    if (id < 2){
      // B-edge pool: facc += we*(S-mu)*alpha, stats inline from partS[jj]
      #pragma unroll
      for (int n=0;n<2;n++){
        int cn = col0 + wn*32 + n*16 + l16;
        float mu, var; ms_from(part, 6+jj, cn, mu, var);
        float al = alphaB(id, var);
        #pragma unroll
        for (int m=0;m<4;m++){
          int rowb = row0 + wm*64 + m*16 + lq*4;
          #pragma unroll
          for (int r=0;r<4;r++)
            facc[m][n][r] += we * (b2f(st[(long)(rowb+r)*CH + cn]) - mu) * al;
        }
      }
      continue;
    }

    // B-edge GEMM (dense or group); cin = 512
    bool grp = (id >= 5);
    int K = grp ? 128 : 512;
    int act = grp ? id - 5 : id - 2;
    const unsigned short* Abase = st + (grp ? (long)colTile*K : 0);
    const unsigned short* Wbase = Wball + woff(e) + (long)col0*K;
    const float* bias = (grp ? gbB : dbB) + ((long)d_bct[e]*3 + act)*CH;

    const unsigned short* gA = Abase + (long)(row0 + ra)*512 + ca;
    const unsigned short* gB = Wbase + (long)ra*K + ca;

    f32x4 acc[4][2];
    #pragma unroll
    for (int m=0;m<4;m++){ acc[m][0]=(f32x4){0,0,0,0}; acc[m][1]=(f32x4){0,0,0,0}; }

    auto STAGE = [&](int tile, int bsel){
      long kk = (long)tile*32;
      GLOAD16(gA + kk, &LDS[bsel*4096 + t*8]);
      GLOAD16(gB + kk, &LDS[12288 + bsel*4096 + t*8]);
    };

    int nk = K >> 5;
    __builtin_amdgcn_s_barrier();   // prior edge's LDS readers are done
    STAGE(0, 0);
    STAGE(1, 1);
    int cb = 0;
    for (int kt = 0; kt < nk; ++kt){
      if (kt+1 < nk) { asm volatile("s_waitcnt vmcnt(2)" ::: "memory"); }
      else           { asm volatile("s_waitcnt vmcnt(0)" ::: "memory"); }
      __builtin_amdgcn_s_barrier();
      if (kt+2 < nk) STAGE(kt+2, (cb >= 1) ? cb-1 : cb+2);
      const unsigned short* pA = &LDS[cb*4096];
      const unsigned short* pB = &LDS[12288 + cb*4096];
      short8 a[4], b[2];
      #pragma unroll
      for (int m=0;m<4;m++) a[m] = *(const short8*)(pA + aoff[m]);
      #pragma unroll
      for (int n=0;n<2;n++) b[n] = *(const short8*)(pB + boff[n]);
      #pragma unroll
      for (int m=0;m<4;m++)
        #pragma unroll
        for (int n=0;n<2;n++)
          acc[m][n] = __builtin_amdgcn_mfma_f32_16x16x32_bf16(a[m], b[n], acc[m][n], 0,0,0);
      cb = (cb+1 == 3) ? 0 : cb+1;
    }

    #pragma unroll
    for (int n=0;n<2;n++){
      int cn = col0 + wn*32 + n*16 + l16;
      float bv = bias[cn];
      #pragma unroll
      for (int m=0;m<4;m++)
        #pragma unroll
        for (int r=0;r<4;r++)
          facc[m][n][r] += we * actf(act, acc[m][n][r] + bv);
    }
  }

  // epilogue: write state (bf16) + stats, or final output (fp32)
  #pragma unroll
  for (int n=0;n<2;n++){
    int cn = col0 + wn*32 + n*16 + l16;
    float cs = 0.f, cq = 0.f;
    #pragma unroll
    for (int m=0;m<4;m++){
      int rowb = row0 + wm*64 + m*16 + lq*4;
      #pragma unroll
      for (int r=0;r<4;r++){
        long off = (long)(rowb+r)*CH + cn;
        float v = facc[m][n][r];
        if (node == 6) outf[off] = v;
        else { sbout[off] = f2b(v); cs += v; cq += v*v; }
      }
    }
    if (node < 6) col_stats_atomic(cs, cq, cn, 6+node, partw);
  }
}

extern "C" void kernel_launch(void* const* d_in, const int* in_sizes, int n_in,
                              void* d_out, int out_size, void* d_ws, size_t ws_size,
                              hipStream_t stream)
{
  const float* x   = (const float*)d_in[0];
  const float* ap  = (const float*)d_in[1];
  const float* gum = (const float*)d_in[2];
  const float* dwA = (const float*)d_in[3];
  const float* dbA = (const float*)d_in[4];
  const float* gwA = (const float*)d_in[5];
  const float* gbA = (const float*)d_in[6];
  const float* pwA = (const float*)d_in[7];
  const float* dwB = (const float*)d_in[8];
  const float* dbB = (const float*)d_in[9];
  const float* gwB = (const float*)d_in[10];
  const float* gbB = (const float*)d_in[11];
  float* out = (float*)d_out;

  char* ws = (char*)d_ws;
  size_t cur = 0;
  auto alloc = [&](size_t bytes)->void*{
    size_t o = cur; cur += (bytes + 255) & ~(size_t)255; return (void*)(ws + o);
  };
  int*   idx  = (int*)  alloc(21*sizeof(int));
  float* wsc  = (float*)alloc(21*sizeof(float));
  float* part = (float*)alloc((size_t)12*CH*2*sizeof(float));   // slots 0..5 A, 6..11 states
  unsigned short* Wball = (unsigned short*)alloc((size_t)7077888*sizeof(unsigned short));
  unsigned short* pre6  = (unsigned short*)alloc((size_t)BATCH*CH*sizeof(unsigned short));
  unsigned short* xb    = (unsigned short*)alloc((size_t)BATCH*1024*sizeof(unsigned short));
  unsigned short* sb[5];
  for (int i=0;i<5;i++)
    sb[i] = (unsigned short*)alloc((size_t)BATCH*CH*sizeof(unsigned short));

  if (cur > ws_size){
    hipLaunchKernelGGL(k_sentinel, dim3(1), dim3(1), 0, stream, out);
    return;
  }

  hipMemsetAsync(part, 0, (size_t)12*CH*2*sizeof(float), stream);
  hipLaunchKernelGGL(k_f2b4, dim3(2048), dim3(256), 0, stream, x, xb, (long)BATCH*1024/4);
  hipLaunchKernelGGL(k_index, dim3(1), dim3(32), 0, stream, ap, gum, idx, wsc);
  hipLaunchKernelGGL(k_wconv_all, dim3(21*128), dim3(256), 0, stream,
                     idx, dwA, pwA, gwA, dwB, gwB, Wball);

  // batched A-edge phase (all depend only on x); inline partA stats
  hipLaunchKernelGGL(k_gemmA_all, dim3(6*256), dim3(512), 0, stream,
                     xb, Wball, sb[0], sb[1], sb[2], sb[3], sb[4], pre6,
                     dbA, gbA, idx, wsc, part);
  // node 1 finalize (pool transform / zero / stats)
  hipLaunchKernelGGL(k_fix1, dim3(512), dim3(512), 0, stream,
                     sb[0], part, part, idx, wsc);

  // node chain (stats fully inline)
  for (int node = 2; node <= 6; node++){
    const unsigned short* pre = (node < 6) ? sb[node-1] : pre6;
    unsigned short* sbout = (node < 6) ? sb[node-1] : sb[0] /*unused*/;
    hipLaunchKernelGGL(k_fused, dim3(512), dim3(512), 0, stream,
                       node, pre, sb[0], sb[1], sb[2], sb[3], sb[4],
                       sbout, out, Wball, dbB, gbB, part, part, idx, wsc);
  }
}

// Round 15
// 406.027 us; speedup vs baseline: 1.1014x; 1.1014x over previous
//
#include <hip/hip_runtime.h>

#define BATCH 16384
#define CH 512
#define EPSBN 1e-5f

typedef __attribute__((ext_vector_type(8))) short short8;
typedef __attribute__((ext_vector_type(4))) float f32x4;
typedef __attribute__((ext_vector_type(4))) unsigned short ushort4v;

#define GLOAD16(gp, lp) __builtin_amdgcn_global_load_lds( \
    (const __attribute__((address_space(1))) void*)(gp),  \
    (__attribute__((address_space(3))) void*)(lp), 16, 0, 0)

// edge table: etab[node-1][j] = edge id; bct[e] = B-weight counter
__constant__ int d_etab[6][6] = {
  {0,0,0,0,0,0},
  {1,6,0,0,0,0},
  {2,7,11,0,0,0},
  {3,8,12,15,0,0},
  {4,9,13,16,18,0},
  {5,10,14,17,19,20}};
__constant__ int d_bct[21] = {0,0,0,0,0,0, 0,1,3,6,10, 2,4,7,11, 5,8,12, 9,13, 14};

static __device__ __forceinline__ long woff(int e){
  return (e < 6) ? (long)e*524288 : 3145728L + (long)d_bct[e]*262144;
}

static __device__ __forceinline__ unsigned short f2b(float f){
  union { float f; unsigned u; } v; v.f = f;
  unsigned r = v.u + 0x7fffu + ((v.u >> 16) & 1u);
  return (unsigned short)(r >> 16);
}
static __device__ __forceinline__ float b2f(unsigned short u){
  union { unsigned u; float f; } v; v.u = ((unsigned)u) << 16; return v.f;
}
static __device__ __forceinline__ float actf(int act, float v){
  if (act == 0) return fmaxf(v, 0.f);
  if (act == 1) return 1.f/(1.f + __expf(-v));
  float e = __expf(2.f*v);                    // tanh = 1 - 2/(e^{2v}+1)
  return 1.f - 2.f/(e + 1.f);
}

// per-column (sum, sumsq) atomic accumulation; 4 lq-lanes share a column
static __device__ __forceinline__ void col_stats_atomic(
    float vs, float vq, int cn, int slot, float* partw){
  vs += __shfl_xor(vs, 16); vs += __shfl_xor(vs, 32);
  vq += __shfl_xor(vq, 16); vq += __shfl_xor(vq, 32);
  if (((threadIdx.x) & 63) < 16){
    atomicAdd(&partw[((long)slot*CH + cn)*2    ], vs);
    atomicAdd(&partw[((long)slot*CH + cn)*2 + 1], vq);
  }
}
// slots: 0..5 = partA[e] (gemmA outputs); 6+j = partS[state j]

static __device__ __forceinline__ void ms_from(const float* part, int slot, int cn,
                                               float& mu, float& var){
  long sl = ((long)slot*CH + cn)*2;
  float s = part[sl], q = part[sl+1];
  mu = s * (1.f/16384.f);
  var = fmaxf(q * (1.f/16384.f) - mu*mu, 0.f);
}
static __device__ __forceinline__ float alphaA(int id, float v){
  float s1r = rsqrtf(v + EPSBN);
  float vz = v / (v + EPSBN);
  return (id==0) ? (s1r * (1.f/9.f) * rsqrtf(vz*(1.f/81.f) + EPSBN))
                 : (s1r * rsqrtf(vz + EPSBN));
}
static __device__ __forceinline__ float alphaB(int id, float v){
  return (id==0) ? ((1.f/9.f) * rsqrtf(v*(1.f/81.f) + EPSBN))
                 : rsqrtf(v + EPSBN);
}

__global__ void k_sentinel(float* out){ out[0] = 1.0e6f; }

// ---------------- index / wscale / stat-need flags ----------------
__global__ void k_index(const float* __restrict__ ap, const float* __restrict__ gum,
                        int* __restrict__ idx, float* __restrict__ wsc,
                        int* __restrict__ statNeed){
  __shared__ int sid[21];
  int e = threadIdx.x;
  if (e < 21){
    const float* a = ap + e*9;
    const float* g = gum + e*9;
    float m = a[0];
    for (int o=1;o<9;o++) m = fmaxf(m, a[o]);
    float s = 0.f;
    for (int o=0;o<9;o++) s += expf(a[o]-m);
    float lse = m + logf(s);
    float lg[9]; float lm = -1e30f;
    for (int o=0;o<9;o++){ lg[o] = (a[o]-lse+g[o]) / 10.0f; lm = fmaxf(lm, lg[o]); }
    float ss = 0.f;
    for (int o=0;o<9;o++) ss += expf(lg[o]-lm);
    int bi = 0; float bp = -1.f;
    for (int o=0;o<9;o++){
      float p = expf(lg[o]-lm)/ss;
      if (p > bp){ bp = p; bi = o; }
    }
    idx[e] = bi;
    wsc[e] = (1.0f - bp) + bp;
    sid[e] = bi;
  }
  __syncthreads();
  if (e < 12){
    int need = 0;
    if (e < 6){
      need = (sid[e] < 2) ? 1 : 0;              // partA[e] used only by pool A-edge
    } else {
      int j = e - 6;                            // state j (1..5 meaningful)
      if (j >= 1){
        for (int n = j+1; n <= 6; ++n)
          if (sid[d_etab[n-1][j]] < 2) need = 1; // some outgoing B-edge is pool
      }
    }
    statNeed[e] = need;
  }
}

// ---------------- fp32 -> bf16 (vector4, grid-stride) ----------------
__global__ void k_f2b4(const float* __restrict__ in, unsigned short* __restrict__ outp, long n4){
  long stride = (long)gridDim.x*blockDim.x;
  for (long i = (long)blockIdx.x*blockDim.x + threadIdx.x; i < n4; i += stride){
    const float4 v = ((const float4*)in)[i];
    ushort4v o;
    o[0] = f2b(v.x); o[1] = f2b(v.y); o[2] = f2b(v.z); o[3] = f2b(v.w);
    ((ushort4v*)outp)[i] = o;
  }
}

// ---------------- all selected weights -> bf16 slots ----------------
__global__ void k_wconv_all(const int* __restrict__ idxp,
                            const float* __restrict__ dwA, const float* __restrict__ pwA,
                            const float* __restrict__ gwA, const float* __restrict__ dwB,
                            const float* __restrict__ gwB,
                            unsigned short* __restrict__ Wball){
  int e = blockIdx.x >> 7;          // 21 edges x 128 blocks
  int blk = blockIdx.x & 127;
  int id = idxp[e];
  const float* src; long n;
  if (e < 6){
    int a = e;
    if (id >= 2 && id <= 4){ n = 524288; src = dwA + ((long)a*3 + (id-2))*n; }
    else if (id < 2)       { n = 524288; src = pwA + ((long)a*2 + id)*n; }
    else if (id <= 7)      { n = 131072; src = gwA + ((long)a*3 + (id-5))*131072; }
    else return;
  } else {
    int b = d_bct[e];
    if (id >= 2 && id <= 4)     { n = 262144; src = dwB + ((long)b*3 + (id-2))*n; }
    else if (id >= 5 && id <= 7){ n = 65536;  src = gwB + ((long)b*3 + (id-5))*65536; }
    else return;
  }
  unsigned short* dst = Wball + woff(e);
  long n4 = n >> 2;
  long stride = 128*256;
  for (long i = (long)blk*256 + threadIdx.x; i < n4; i += stride){
    const float4 v = ((const float4*)src)[i];
    ushort4v o;
    o[0] = f2b(v.x); o[1] = f2b(v.y); o[2] = f2b(v.z); o[3] = f2b(v.w);
    ((ushort4v*)dst)[i] = o;
  }
}

// ---------------- batched A-edge GEMMs (all 6 edges fed by x) + gated stats ----------------
__global__ __launch_bounds__(512, 4) void k_gemmA_all(
    const unsigned short* __restrict__ xb, const unsigned short* __restrict__ Wball,
    unsigned short* __restrict__ s0, unsigned short* __restrict__ s1,
    unsigned short* __restrict__ s2, unsigned short* __restrict__ s3,
    unsigned short* __restrict__ s4, unsigned short* __restrict__ pre6,
    const float* __restrict__ dbA, const float* __restrict__ gbA,
    const int* __restrict__ idxp, const float* __restrict__ wscp,
    float* __restrict__ partw)
{
  int e = blockIdx.x >> 9;
  int id = idxp[e];
  if (id == 8) return;
  unsigned short* target;
  switch(e){ case 0: target=s0; break; case 1: target=s1; break; case 2: target=s2; break;
             case 3: target=s3; break; case 4: target=s4; break; default: target=pre6; }
  bool pool = (id < 2);
  bool grp = (id >= 5);
  int K = grp ? 256 : 1024;
  int act = pool ? 0 : (grp ? id-5 : id-2);
  float we = wscp[e];

  int inner = blockIdx.x & 511;
  int lg = (inner & 7) * 64 + (inner >> 3);
  int rowTile = lg >> 2, colTile = lg & 3;
  int row0 = rowTile * 128, col0 = colTile * 128;

  int t = threadIdx.x;
  int lane = t & 63, wave = t >> 6;
  int wm = wave >> 2, wn = wave & 3;
  int l16 = lane & 15, lq = lane >> 4;

  __shared__ unsigned short LDS[24576];   // A x3 @0/4096/8192, B x3 @12288+

  int ra = t >> 2;
  int ca = (((t & 3) ^ ((ra >> 1) & 3)) << 3);
  int aoff[4], boff[2];
  #pragma unroll
  for (int m=0;m<4;m++){ int R = wm*64 + m*16 + l16; aoff[m] = R*32 + ((lq ^ ((R>>1)&3))<<3); }
  #pragma unroll
  for (int n=0;n<2;n++){ int C = wn*32 + n*16 + l16; boff[n] = C*32 + ((lq ^ ((C>>1)&3))<<3); }

  const unsigned short* Abase = xb + (grp ? (long)colTile*K : 0);
  const unsigned short* Wbase = Wball + (long)e*524288 + (long)col0*K;
  const unsigned short* gA = Abase + (long)(row0 + ra)*1024 + ca;
  const unsigned short* gB = Wbase + (long)ra*K + ca;
  const float* bias = (grp ? gbA : dbA) + ((long)e*3 + act)*CH;

  f32x4 acc[4][2];
  #pragma unroll
  for (int m=0;m<4;m++){ acc[m][0]=(f32x4){0,0,0,0}; acc[m][1]=(f32x4){0,0,0,0}; }

  auto STAGE = [&](int tile, int bsel){
    long kk = (long)tile*32;
    GLOAD16(gA + kk, &LDS[bsel*4096 + t*8]);
    GLOAD16(gB + kk, &LDS[12288 + bsel*4096 + t*8]);
  };

  int nk = K >> 5;
  STAGE(0, 0);
  STAGE(1, 1);
  int cb = 0;
  for (int kt = 0; kt < nk; ++kt){
    if (kt+1 < nk) { asm volatile("s_waitcnt vmcnt(2)" ::: "memory"); }
    else           { asm volatile("s_waitcnt vmcnt(0)" ::: "memory"); }
    __builtin_amdgcn_s_barrier();
    if (kt+2 < nk) STAGE(kt+2, (cb >= 1) ? cb-1 : cb+2);
    const unsigned short* pA = &LDS[cb*4096];
    const unsigned short* pB = &LDS[12288 + cb*4096];
    short8 a[4], b[2];
    #pragma unroll
    for (int m=0;m<4;m++){
      a[m] = *(const short8*)(pA + aoff[m]);
      if (pool){
        #pragma unroll
        for (int q=0;q<8;q++) a[m][q] = (a[m][q] < (short)0) ? (short)0 : a[m][q];
      }
    }
    #pragma unroll
    for (int n=0;n<2;n++) b[n] = *(const short8*)(pB + boff[n]);
    #pragma unroll
    for (int m=0;m<4;m++)
      #pragma unroll
      for (int n=0;n<2;n++)
        acc[m][n] = __builtin_amdgcn_mfma_f32_16x16x32_bf16(a[m], b[n], acc[m][n], 0,0,0);
    cb = (cb+1 == 3) ? 0 : cb+1;
  }

  #pragma unroll
  for (int n=0;n<2;n++){
    int cn = col0 + wn*32 + n*16 + l16;
    float bv = pool ? 0.f : bias[cn];
    float cs = 0.f, cq = 0.f;
    #pragma unroll
    for (int m=0;m<4;m++)
      #pragma unroll
      for (int r=0;r<4;r++){
        int row = row0 + wm*64 + m*16 + lq*4 + r;
        long off = (long)row*CH + cn;
        float v = pool ? acc[m][n][r] : (we * actf(act, acc[m][n][r] + bv));
        target[off] = f2b(v);
        cs += v; cq += v*v;
      }
    if (pool) col_stats_atomic(cs, cq, cn, e, partw);  // partA only read for pool
  }
}

// ---------------- node-1 finalize: s1 transform (pool/zero) + gated stats ----------------
__global__ __launch_bounds__(512, 4) void k_fix1(
    unsigned short* __restrict__ s1, const float* __restrict__ part,
    float* __restrict__ partw, const int* __restrict__ idxp,
    const float* __restrict__ wscp, const int* __restrict__ statNeed)
{
  int id = idxp[0];
  int needS = statNeed[7];
  if (id >= 2 && id != 8 && !needS) return;   // dense/group & no stats needed: nothing to do
  float we = wscp[0];

  int bid = blockIdx.x;
  int lg = (bid & 7) * 64 + (bid >> 3);
  int rowTile = lg >> 2, colTile = lg & 3;
  int row0 = rowTile * 128, col0 = colTile * 128;

  int t = threadIdx.x;
  int lane = t & 63, wave = t >> 6;
  int wm = wave >> 2, wn = wave & 3;
  int l16 = lane & 15, lq = lane >> 4;

  #pragma unroll
  for (int n=0;n<2;n++){
    int cn = col0 + wn*32 + n*16 + l16;
    float cs = 0.f, cq = 0.f;
    float mu = 0.f, al = 0.f;
    if (id < 2){
      float var; ms_from(part, 0, cn, mu, var);
      al = alphaA(id, var);
    }
    #pragma unroll
    for (int m=0;m<4;m++)
      #pragma unroll
      for (int r=0;r<4;r++){
        int row = row0 + wm*64 + m*16 + lq*4 + r;
        long off = (long)row*CH + cn;
        float v;
        if (id == 8){ v = 0.f; s1[off] = 0; }
        else if (id < 2){ v = we * (b2f(s1[off]) - mu) * al; s1[off] = f2b(v); }
        else { v = b2f(s1[off]); }
        cs += v; cq += v*v;
      }
    if (needS) col_stats_atomic(cs, cq, cn, 6+1, partw);
  }
}

// ---------------- fused per-node kernel: merge preA + B-edge GEMMs + gated stats ----------------
__global__ __launch_bounds__(512, 4) void k_fused(
    int node,
    const unsigned short* __restrict__ pre,
    const unsigned short* __restrict__ sb0, const unsigned short* __restrict__ sb1,
    const unsigned short* __restrict__ sb2, const unsigned short* __restrict__ sb3,
    const unsigned short* __restrict__ sb4,
    unsigned short* __restrict__ sbout, float* __restrict__ outf,
    const unsigned short* __restrict__ Wball,
    const float* __restrict__ dbB, const float* __restrict__ gbB,
    const float* __restrict__ part, float* __restrict__ partw,
    const int* __restrict__ idxp, const float* __restrict__ wscp,
    const int* __restrict__ statNeed)
{
  int bid = blockIdx.x;
  int lg = (bid & 7) * 64 + (bid >> 3);      // 512 blocks, bijective
  int rowTile = lg >> 2, colTile = lg & 3;
  int row0 = rowTile * 128, col0 = colTile * 128;

  int t = threadIdx.x;
  int lane = t & 63, wave = t >> 6;
  int wm = wave >> 2, wn = wave & 3;
  int l16 = lane & 15, lq = lane >> 4;

  __shared__ unsigned short LDS[24576];   // A x3, B x3

  int ra = t >> 2;
  int ca = (((t & 3) ^ ((ra >> 1) & 3)) << 3);
  int aoff[4], boff[2];
  #pragma unroll
  for (int m=0;m<4;m++){ int R = wm*64 + m*16 + l16; aoff[m] = R*32 + ((lq ^ ((R>>1)&3))<<3); }
  #pragma unroll
  for (int n=0;n<2;n++){ int C = wn*32 + n*16 + l16; boff[n] = C*32 + ((lq ^ ((C>>1)&3))<<3); }

  f32x4 facc[4][2];
  #pragma unroll
  for (int m=0;m<4;m++){ facc[m][0]=(f32x4){0,0,0,0}; facc[m][1]=(f32x4){0,0,0,0}; }

  for (int jj = 0; jj < node; ++jj){
    int e = d_etab[node-1][jj];
    int id = idxp[e];
    if (id == 8) continue;
    float we = wscp[e];

    if (jj == 0){
      // merge precomputed A-edge term (pre aliases sbout; same per-thread offsets)
      if (id < 2){
        #pragma unroll
        for (int n=0;n<2;n++){
          int cn = col0 + wn*32 + n*16 + l16;
          float mu, var; ms_from(part, e, cn, mu, var);
          float al = alphaA(id, var);
          #pragma unroll
          for (int m=0;m<4;m++){
            int rowb = row0 + wm*64 + m*16 + lq*4;
            #pragma unroll
            for (int r=0;r<4;r++)
              facc[m][n][r] += we * (b2f(pre[(long)(rowb+r)*CH + cn]) - mu) * al;
          }
        }
      } else {
        #pragma unroll
        for (int n=0;n<2;n++){
          int cn = col0 + wn*32 + n*16 + l16;
          #pragma unroll
          for (int m=0;m<4;m++){
            int rowb = row0 + wm*64 + m*16 + lq*4;
            #pragma unroll
            for (int r=0;r<4;r++)
              facc[m][n][r] += b2f(pre[(long)(rowb+r)*CH + cn]);
          }
        }
      }
      continue;
    }

    const unsigned short* st;
    switch(jj){ case 1: st=sb0; break; case 2: st=sb1; break;
                case 3: st=sb2; break; case 4: st=sb3; break; default: st=sb4; }

    if (id < 2){
      // B-edge pool: facc += we*(S-mu)*alpha, stats inline from partS[jj]
      #pragma unroll
      for (int n=0;n<2;n++){
        int cn = col0 + wn*32 + n*16 + l16;
        float mu, var; ms_from(part, 6+jj, cn, mu, var);
        float al = alphaB(id, var);
        #pragma unroll
        for (int m=0;m<4;m++){
          int rowb = row0 + wm*64 + m*16 + lq*4;
          #pragma unroll
          for (int r=0;r<4;r++)
            facc[m][n][r] += we * (b2f(st[(long)(rowb+r)*CH + cn]) - mu) * al;
        }
      }
      continue;
    }

    // B-edge GEMM (dense or group); cin = 512
    bool grp = (id >= 5);
    int K = grp ? 128 : 512;
    int act = grp ? id - 5 : id - 2;
    const unsigned short* Abase = st + (grp ? (long)colTile*K : 0);
    const unsigned short* Wbase = Wball + woff(e) + (long)col0*K;
    const float* bias = (grp ? gbB : dbB) + ((long)d_bct[e]*3 + act)*CH;

    const unsigned short* gA = Abase + (long)(row0 + ra)*512 + ca;
    const unsigned short* gB = Wbase + (long)ra*K + ca;

    f32x4 acc[4][2];
    #pragma unroll
    for (int m=0;m<4;m++){ acc[m][0]=(f32x4){0,0,0,0}; acc[m][1]=(f32x4){0,0,0,0}; }

    auto STAGE = [&](int tile, int bsel){
      long kk = (long)tile*32;
      GLOAD16(gA + kk, &LDS[bsel*4096 + t*8]);
      GLOAD16(gB + kk, &LDS[12288 + bsel*4096 + t*8]);
    };

    int nk = K >> 5;
    __builtin_amdgcn_s_barrier();   // prior edge's LDS readers are done
    STAGE(0, 0);
    STAGE(1, 1);
    int cb = 0;
    for (int kt = 0; kt < nk; ++kt){
      if (kt+1 < nk) { asm volatile("s_waitcnt vmcnt(2)" ::: "memory"); }
      else           { asm volatile("s_waitcnt vmcnt(0)" ::: "memory"); }
      __builtin_amdgcn_s_barrier();
      if (kt+2 < nk) STAGE(kt+2, (cb >= 1) ? cb-1 : cb+2);
      const unsigned short* pA = &LDS[cb*4096];
      const unsigned short* pB = &LDS[12288 + cb*4096];
      short8 a[4], b[2];
      #pragma unroll
      for (int m=0;m<4;m++) a[m] = *(const short8*)(pA + aoff[m]);
      #pragma unroll
      for (int n=0;n<2;n++) b[n] = *(const short8*)(pB + boff[n]);
      #pragma unroll
      for (int m=0;m<4;m++)
        #pragma unroll
        for (int n=0;n<2;n++)
          acc[m][n] = __builtin_amdgcn_mfma_f32_16x16x32_bf16(a[m], b[n], acc[m][n], 0,0,0);
      cb = (cb+1 == 3) ? 0 : cb+1;
    }

    #pragma unroll
    for (int n=0;n<2;n++){
      int cn = col0 + wn*32 + n*16 + l16;
      float bv = bias[cn];
      #pragma unroll
      for (int m=0;m<4;m++)
        #pragma unroll
        for (int r=0;r<4;r++)
          facc[m][n][r] += we * actf(act, acc[m][n][r] + bv);
    }
  }

  // epilogue: write state (bf16) + gated stats, or final output (fp32)
  int needS = (node < 6) ? statNeed[6+node] : 0;
  #pragma unroll
  for (int n=0;n<2;n++){
    int cn = col0 + wn*32 + n*16 + l16;
    float cs = 0.f, cq = 0.f;
    #pragma unroll
    for (int m=0;m<4;m++){
      int rowb = row0 + wm*64 + m*16 + lq*4;
      #pragma unroll
      for (int r=0;r<4;r++){
        long off = (long)(rowb+r)*CH + cn;
        float v = facc[m][n][r];
        if (node == 6) outf[off] = v;
        else { sbout[off] = f2b(v); cs += v; cq += v*v; }
      }
    }
    if (needS) col_stats_atomic(cs, cq, cn, 6+node, partw);
  }
}

extern "C" void kernel_launch(void* const* d_in, const int* in_sizes, int n_in,
                              void* d_out, int out_size, void* d_ws, size_t ws_size,
                              hipStream_t stream)
{
  const float* x   = (const float*)d_in[0];
  const float* ap  = (const float*)d_in[1];
  const float* gum = (const float*)d_in[2];
  const float* dwA = (const float*)d_in[3];
  const float* dbA = (const float*)d_in[4];
  const float* gwA = (const float*)d_in[5];
  const float* gbA = (const float*)d_in[6];
  const float* pwA = (const float*)d_in[7];
  const float* dwB = (const float*)d_in[8];
  const float* dbB = (const float*)d_in[9];
  const float* gwB = (const float*)d_in[10];
  const float* gbB = (const float*)d_in[11];
  float* out = (float*)d_out;

  char* ws = (char*)d_ws;
  size_t cur = 0;
  auto alloc = [&](size_t bytes)->void*{
    size_t o = cur; cur += (bytes + 255) & ~(size_t)255; return (void*)(ws + o);
  };
  int*   idx  = (int*)  alloc(21*sizeof(int));
  float* wsc  = (float*)alloc(21*sizeof(float));
  int*   stn  = (int*)  alloc(12*sizeof(int));
  float* part = (float*)alloc((size_t)12*CH*2*sizeof(float));   // slots 0..5 A, 6..11 states
  unsigned short* Wball = (unsigned short*)alloc((size_t)7077888*sizeof(unsigned short));
  unsigned short* pre6  = (unsigned short*)alloc((size_t)BATCH*CH*sizeof(unsigned short));
  unsigned short* xb    = (unsigned short*)alloc((size_t)BATCH*1024*sizeof(unsigned short));
  unsigned short* sb[5];
  for (int i=0;i<5;i++)
    sb[i] = (unsigned short*)alloc((size_t)BATCH*CH*sizeof(unsigned short));

  if (cur > ws_size){
    hipLaunchKernelGGL(k_sentinel, dim3(1), dim3(1), 0, stream, out);
    return;
  }

  hipMemsetAsync(part, 0, (size_t)12*CH*2*sizeof(float), stream);
  hipLaunchKernelGGL(k_f2b4, dim3(2048), dim3(256), 0, stream, x, xb, (long)BATCH*1024/4);
  hipLaunchKernelGGL(k_index, dim3(1), dim3(32), 0, stream, ap, gum, idx, wsc, stn);
  hipLaunchKernelGGL(k_wconv_all, dim3(21*128), dim3(256), 0, stream,
                     idx, dwA, pwA, gwA, dwB, gwB, Wball);

  // batched A-edge phase (all depend only on x); pool-gated partA stats
  hipLaunchKernelGGL(k_gemmA_all, dim3(6*512), dim3(512), 0, stream,
                     xb, Wball, sb[0], sb[1], sb[2], sb[3], sb[4], pre6,
                     dbA, gbA, idx, wsc, part);
  // node 1 finalize (pool transform / zero / gated stats)
  hipLaunchKernelGGL(k_fix1, dim3(512), dim3(512), 0, stream,
                     sb[0], part, part, idx, wsc, stn);

  // node chain (stats fully inline, gated)
  for (int node = 2; node <= 6; node++){
    const unsigned short* pre = (node < 6) ? sb[node-1] : pre6;
    unsigned short* sbout = (node < 6) ? sb[node-1] : sb[0] /*unused*/;
    hipLaunchKernelGGL(k_fused, dim3(512), dim3(512), 0, stream,
                       node, pre, sb[0], sb[1], sb[2], sb[3], sb[4],
                       sbout, out, Wball, dbB, gbB, part, part, idx, wsc, stn);
  }
}